// Round 17
// baseline (176.549 us; speedup 1.0000x reference)
//
#include <hip/hip_runtime.h>
#include <hip/hip_bf16.h>

using bf16 = __hip_bfloat16;
typedef float f32;
typedef __attribute__((ext_vector_type(8))) short bf16x8;
typedef __attribute__((ext_vector_type(4))) float f32x4;
typedef __attribute__((ext_vector_type(4))) unsigned short u16x4;
typedef __attribute__((ext_vector_type(8))) unsigned short u16x8;

static __device__ __forceinline__ f32 siluf(f32 v){ return v / (1.f + __expf(-v)); }
static __device__ __forceinline__ unsigned short f2bf(f32 v){
  __hip_bfloat16 h=__float2bfloat16(v); return *(unsigned short*)&h;
}
static __device__ __forceinline__ f32 bfr2f(unsigned short u){
  unsigned int x=((unsigned int)u)<<16; return __uint_as_float(x);
}

// spatial position of sequence index p for scan direction dir (H=W=64, L=4096)
static __device__ __forceinline__ int pos_of(int dir, int p){
  if(dir==0) return p;
  if(dir==1) return ((p&63)<<6) | (p>>6);
  if(dir==2) return 4095-p;
  int q = 4095-p; return ((q&63)<<6) | (q>>6);
}

// inclusive wave-64 prefix scan
static __device__ __forceinline__ f32 wave_iscan(f32 v, int lane){
  #pragma unroll
  for(int off=1; off<64; off<<=1){
    f32 u=__shfl_up(v,off,64);
    if(lane>=off) v+=u;
  }
  return v;
}
// inclusive wave-64 suffix scan (v[lane] = sum_{j>=lane})
static __device__ __forceinline__ f32 wave_sscan(f32 v, int lane){
  #pragma unroll
  for(int off=1; off<64; off<<=1){
    f32 u=__shfl_down(v,off,64);
    if(lane<64-off) v+=u;
  }
  return v;
}

// ---------------- Kernel W: weights -> bf16 fragment layout + Dsum -------------
__global__ __launch_bounds__(256) void k_wcvt_all(const f32* __restrict__ xpw, const f32* __restrict__ ipw,
                                                  const f32* __restrict__ opw, const f32* __restrict__ dsw,
                                                  unsigned short* __restrict__ Wx, unsigned short* __restrict__ Wi,
                                                  unsigned short* __restrict__ Wo, f32* __restrict__ Dsum){
  const int t=blockIdx.x*256+threadIdx.x;
  if(t<3840){
    const int g=t%24, n=t/24, nt=n>>4, l=n&15;
    const int dir=n/40, cc=n-dir*40;
    u16x8 w={0,0,0,0,0,0,0,0};
    if(cc<38){
      const f32* p=&xpw[(size_t)dir*7296+cc*192+g*8];
      #pragma unroll
      for(int j=0;j<8;j++) w[j]=f2bf(p[j]);
    }
    *(u16x8*)&Wx[((size_t)(nt*24+g)*16+l)*8]=w;
  } else if(t<8448){
    const int i=t-3840, g=i%12, n=i/12, nt=n>>4, l=n&15;
    const f32* p=&ipw[(size_t)n*96+g*8];
    u16x8 w;
    #pragma unroll
    for(int j=0;j<8;j++) w[j]=f2bf(p[j]);
    *(u16x8*)&Wi[((size_t)(nt*12+g)*16+l)*8]=w;
  } else if(t<10752){
    const int i=t-8448, g=i%24, n=i/24, nt=n>>4, l=n&15;
    const f32* p=&opw[(size_t)n*192+g*8];
    u16x8 w;
    #pragma unroll
    for(int j=0;j<8;j++) w[j]=f2bf(p[j]);
    *(u16x8*)&Wo[((size_t)(nt*24+g)*16+l)*8]=w;
  } else if(t<10944){
    const int ch=t-10752;
    Dsum[ch]=dsw[ch]+dsw[192+ch]+dsw[384+ch]+dsw[576+ch];
  }
}

// ---------------- Kernel A (MFMA): xz = x @ in_proj_w.T ; split, silu ----------
// BM=32, 1024 blocks (4 blk/CU). Wave: mt=wv&1, nt strip (wv>>1)*12.
__global__ __launch_bounds__(256) void k_inproj(const f32* __restrict__ x, const unsigned short* __restrict__ Wi,
                                                f32* __restrict__ xh_raw, f32* __restrict__ z){
  __shared__ unsigned short Ald[12*32*8];      // 6 KB
  const int m0=blockIdx.x*32, tid=threadIdx.x;
  for(int i=tid;i<384;i+=256){
    int r=i&31, g=i>>5;
    const f32* p=&x[(size_t)(m0+r)*96+g*8];
    float4 v0=*(const float4*)p, v1=*(const float4*)(p+4);
    u16x8 w={f2bf(v0.x),f2bf(v0.y),f2bf(v0.z),f2bf(v0.w),
             f2bf(v1.x),f2bf(v1.y),f2bf(v1.z),f2bf(v1.w)};
    *(u16x8*)&Ald[(size_t)(g*32+r)*8]=w;
  }
  __syncthreads();
  const int wv=tid>>6, lane=tid&63, l15=lane&15, l4=lane>>4;
  const int mt=wv&1, ntb=(wv>>1)*12;
  f32x4 acc[12];
  #pragma unroll
  for(int j=0;j<12;j++){ f32x4 zz={0.f,0.f,0.f,0.f}; acc[j]=zz; }
  #pragma unroll
  for(int ks=0;ks<3;ks++){
    const int g=ks*4+l4;
    bf16x8 a=*(const bf16x8*)&Ald[(size_t)(g*32+mt*16+l15)*8];
    #pragma unroll
    for(int j=0;j<12;j++){
      bf16x8 bfr=*(const bf16x8*)&Wi[((size_t)((ntb+j)*12+g)*16+l15)*8];
      acc[j]=__builtin_amdgcn_mfma_f32_16x16x32_bf16(a,bfr,acc[j],0,0,0);
    }
  }
  const int rowb=m0+mt*16+l4*4;
  #pragma unroll
  for(int j=0;j<12;j++){
    int col=(ntb+j)*16+l15;
    #pragma unroll
    for(int r=0;r<4;r++){
      int row=rowb+r; f32 v=acc[j][r];
      if(col<192) xh_raw[(size_t)row*192+col]=v;
      else        z[(size_t)row*192+(col-192)]=siluf(v);
    }
  }
}

// ---------------- Kernel B: depthwise 3x3 conv + bias + silu -> xh (f32) + xhb --
__global__ __launch_bounds__(256) void k_conv(const f32* __restrict__ xh_raw, const f32* __restrict__ cw,
                                              const f32* __restrict__ cb, f32* __restrict__ xh,
                                              unsigned short* __restrict__ xhb){
  __shared__ f32 wsm[192][9];
  __shared__ f32 bsm[192];
  const int tid=threadIdx.x;
  for(int i=tid;i<1728;i+=256) wsm[i/9][i%9]=cw[i];
  for(int i=tid;i<192;i+=256) bsm[i]=cb[i];
  __syncthreads();
  const int idx=blockIdx.x*256+tid;
  const int c4=idx%48, j=(idx/48)&63, ii0=(idx/3072)&63, b=idx/196608;
  const int c0=c4*4;
  f32 acc[4]={bsm[c0],bsm[c0+1],bsm[c0+2],bsm[c0+3]};
  #pragma unroll
  for(int a=0;a<3;a++){
    int ii=ii0+a-1; if(ii<0||ii>63) continue;
    #pragma unroll
    for(int bb=0;bb<3;bb++){
      int jj=j+bb-1; if(jj<0||jj>63) continue;
      float4 v=*(const float4*)&xh_raw[((size_t)(b*4096)+(ii*64+jj))*192 + c0];
      int t=a*3+bb;
      acc[0]+=v.x*wsm[c0][t]; acc[1]+=v.y*wsm[c0+1][t];
      acc[2]+=v.z*wsm[c0+2][t]; acc[3]+=v.w*wsm[c0+3][t];
    }
  }
  float4 o; o.x=siluf(acc[0]); o.y=siluf(acc[1]); o.z=siluf(acc[2]); o.w=siluf(acc[3]);
  ((float4*)xh)[idx]=o;
  u16x4 w={f2bf(o.x),f2bf(o.y),f2bf(o.z),f2bf(o.w)};
  *(u16x4*)&xhb[(size_t)idx*4]=w;
}

// ---------------- Kernel C (MFMA): x_dbl = xhb @ Wx^T -> dt(softplus), B, C ----
// BM=32, 1024 blocks. Staging = pure bf16 copy from xhb.
__global__ __launch_bounds__(256) void k_xdbl(const unsigned short* __restrict__ xhb,
                                              const unsigned short* __restrict__ Wfrag,
                                              const f32* __restrict__ dtb, f32* __restrict__ dt_sp,
                                              f32* __restrict__ Bg, f32* __restrict__ Cg){
  __shared__ unsigned short Ald[24*32*8];      // 12 KB
  const int m0=blockIdx.x*32;
  const int tid=threadIdx.x;
  for(int i=tid;i<768;i+=256){
    int r=i&31, g=i>>5;
    u16x8 w=*(const u16x8*)&xhb[(size_t)(m0+r)*192+g*8];
    *(u16x8*)&Ald[(size_t)(g*32+r)*8]=w;
  }
  __syncthreads();
  const int wv=tid>>6, lane=tid&63, l15=lane&15, l4=lane>>4;
  const int mt=wv&1, ntb=(wv>>1)*5;
  f32x4 acc[5];
  #pragma unroll
  for(int j=0;j<5;j++){ f32x4 zz={0.f,0.f,0.f,0.f}; acc[j]=zz; }
  #pragma unroll
  for(int ks=0;ks<6;ks++){
    const int g=ks*4+l4;
    bf16x8 a=*(const bf16x8*)&Ald[(size_t)(g*32 + mt*16 + l15)*8];
    #pragma unroll
    for(int j=0;j<5;j++){
      bf16x8 bfr=*(const bf16x8*)&Wfrag[((size_t)((ntb+j)*24+g)*16+l15)*8];
      acc[j]=__builtin_amdgcn_mfma_f32_16x16x32_bf16(a,bfr,acc[j],0,0,0);
    }
  }
  const int rowb=m0 + mt*16 + l4*4;
  #pragma unroll
  for(int j=0;j<5;j++){
    int n=(ntb+j)*16+l15, dir=n/40, cc=n-dir*40;
    if(cc>=38) continue;
    #pragma unroll
    for(int r=0;r<4;r++){
      size_t pix=(size_t)(rowb+r);
      f32 v=acc[j][r];
      if(cc<6){ f32 xv=v+dtb[dir*6+cc]; dt_sp[pix*24+dir*6+cc]=(xv>20.f)? xv : log1pf(__expf(xv)); }
      else if(cc<22){ Bg[(pix*4+dir)*16+(cc-6)]=v; }
      else          { Cg[(pix*4+dir)*16+(cc-22)]=v; }
    }
  }
}

// ---------------- Kernel D1 (MFMA): S_loc = e63 * (B' @ Bt^T) ------------------
#define LDK1 72
__global__ __launch_bounds__(384) void k_chunk1(const unsigned short* __restrict__ xhb, const f32* __restrict__ Bg,
      const f32* __restrict__ dt_sp, const f32* __restrict__ Alogs, f32* __restrict__ S, f32* __restrict__ ach){
  __shared__ unsigned short Bp[192*LDK1];
  __shared__ unsigned short BtT[16*LDK1];
  __shared__ f32 dtl[64][6], w1l[64][6];
  __shared__ f32 e63[6];
  const int c=blockIdx.x, dir=blockIdx.y, b=blockIdx.z, c0=c*64, tid=threadIdx.x;
  { int r=tid/6, q=tid-r*6; size_t pix=(size_t)b*4096+pos_of(dir,c0+r);
    dtl[r][q]=dt_sp[pix*24+dir*6+q]; }
  if(tid<256){
    int r=tid>>2,q=tid&3; size_t pix=(size_t)b*4096+pos_of(dir,c0+r);
    float4 bv=*(const float4*)&Bg[(pix*4+dir)*16+q*4];
    BtT[(4*q+0)*LDK1+r]=f2bf(bv.x); BtT[(4*q+1)*LDK1+r]=f2bf(bv.y);
    BtT[(4*q+2)*LDK1+r]=f2bf(bv.z); BtT[(4*q+3)*LDK1+r]=f2bf(bv.w);
  }
  __syncthreads();
  const int wv=tid>>6, lane=tid&63;
  {
    f32 A=-__expf(Alogs[dir*6+wv]);
    f32 dv=dtl[lane][wv];
    f32 v=wave_iscan(dv*A,lane);
    w1l[lane][wv]=__expf(-v)*dv;
    if(lane==63){
      f32 e=__expf(v);
      e63[wv]=e;
      ach[((size_t)(b*64+c))*24+dir*6+wv]=e;
    }
  }
  __syncthreads();
  for(int u=tid;u<768;u+=384){
    int sg=u/48, q=u-sg*48, head=q>>3;
    f32 vv[4][4];
    #pragma unroll
    for(int j=0;j<4;j++){
      int s=sg*4+j;
      u16x4 xv=*(const u16x4*)&xhb[(size_t)(b*4096+pos_of(dir,c0+s))*192+q*4];
      f32 w1=w1l[s][head];
      vv[j][0]=bfr2f(xv[0])*w1; vv[j][1]=bfr2f(xv[1])*w1;
      vv[j][2]=bfr2f(xv[2])*w1; vv[j][3]=bfr2f(xv[3])*w1;
    }
    #pragma unroll
    for(int cc=0;cc<4;cc++){
      u16x4 w={f2bf(vv[0][cc]),f2bf(vv[1][cc]),f2bf(vv[2][cc]),f2bf(vv[3][cc])};
      *(u16x4*)&Bp[(4*q+cc)*LDK1+sg*4]=w;
    }
  }
  __syncthreads();
  const int l15=lane&15, l4=lane>>4;
  f32x4 acc[2];
  { f32x4 zz={0.f,0.f,0.f,0.f}; acc[0]=zz; acc[1]=zz; }
  #pragma unroll
  for(int i=0;i<2;i++){
    int mt=wv+6*i;
    #pragma unroll
    for(int ks=0;ks<2;ks++){
      int kg=ks*4+l4;
      bf16x8 a=*(const bf16x8*)&Bp[(size_t)(mt*16+l15)*LDK1+kg*8];
      bf16x8 bb=*(const bf16x8*)&BtT[(size_t)l15*LDK1+kg*8];
      acc[i]=__builtin_amdgcn_mfma_f32_16x16x32_bf16(a,bb,acc[i],0,0,0);
    }
  }
  const size_t base=(((size_t)(b*64+c))*24+dir*6)*512;
  #pragma unroll
  for(int i=0;i<2;i++){
    int mt=wv+6*i;
    #pragma unroll
    for(int r=0;r<4;r++){
      int ch=mt*16+l4*4+r, head=ch>>5, d=ch&31;
      S[base+(size_t)head*512+d*16+l15]=acc[i][r]*e63[head];
    }
  }
}

// ---------------- Kernel D2: serial inter-chunk scan (4x unrolled prefetch) ----
__global__ __launch_bounds__(256) void k_scan(f32* __restrict__ S, const f32* __restrict__ ach){
  const int g=blockIdx.x*256+threadIdx.x;
  const int b=g/12288, rem=g%12288, h=rem/512;
  size_t base=(size_t)b*786432 + rem;
  const f32* ap=&ach[(size_t)b*1536 + h];
  f32 st=0.f;
  #pragma unroll 1
  for(int c=0;c<64;c+=4){
    f32 a0=ap[(c+0)*24], a1=ap[(c+1)*24], a2=ap[(c+2)*24], a3=ap[(c+3)*24];
    f32* p0=&S[base+(size_t)(c+0)*12288];
    f32* p1=&S[base+(size_t)(c+1)*12288];
    f32* p2=&S[base+(size_t)(c+2)*12288];
    f32* p3=&S[base+(size_t)(c+3)*12288];
    f32 s0=*p0, s1=*p1, s2=*p2, s3=*p3;
    *p0=st; st=a0*st+s0;
    *p1=st; st=a1*st+s1;
    *p2=st; st=a2*st+s2;
    *p3=st; st=a3*st+s3;
  }
}

// ---------------- Kernel D3 (MFMA, merged dirs+halves): 768 thr = 12 waves ------
// B' built from fp32 xh (single bf16 rounding — precision anchor for y_intra).
#define LDK 104
__global__ __launch_bounds__(768) void k_chunk2(const f32* __restrict__ xh, const f32* __restrict__ Bg,
      const f32* __restrict__ Cg, const f32* __restrict__ dt_sp, const f32* __restrict__ Sprev,
      const f32* __restrict__ Alogs,
      f32* __restrict__ ym0, f32* __restrict__ ym1){
  __shared__ unsigned short Alds[64*LDK];   // 13.3 KB: [CBtri | Ct | 0]
  __shared__ unsigned short Blds[192*LDK];  // 39.9 KB: [x*w1 ; prevT ; 0]
  __shared__ unsigned short Btf[64*32];     // 4 KB
  __shared__ f32 w1l[2][64][6], erowl[2][64][6];  // 6 KB  (total 63.5 KB -> 2 blk/CU)
  const int c=blockIdx.x, b=blockIdx.y, pair=blockIdx.z;
  const int c0=c*64, tid=threadIdx.x;
  f32* __restrict__ ym = pair? ym1 : ym0;
  const int wv=tid>>6, lane=tid&63, l15=lane&15, l4=lane>>4;
  // upfront scans for both dirs
  {
    int ds=(wv>=6)?1:0, head=ds? wv-6 : wv;
    int dirs=pair+2*ds;
    f32 Aa=-__expf(Alogs[dirs*6+head]);
    size_t pixL=(size_t)b*4096 + (pair==0 ? (c0+lane) : (lane*64+c));
    f32 dv=dt_sp[pixL*24+dirs*6+head];
    f32 sc = ds? wave_sscan(dv*Aa,lane) : wave_iscan(dv*Aa,lane);
    w1l[ds][lane][head]=__expf(-sc)*dv;
    erowl[ds][lane][head]=__expf(sc);
  }
  f32 vsum[4][4];
  #pragma unroll
  for(int mt=0;mt<4;mt++){
    #pragma unroll
    for(int r=0;r<4;r++) vsum[mt][r]=0.f;
  }
  const int gch=wv*16+l15, ohead=gch>>5;
  #pragma unroll
  for(int d=0;d<2;d++){
    const int dir=pair+d*2;
    const int cd=d? (63-c) : c;
    if(d) __syncthreads();
    if(tid<256){
      int r=tid>>2,q=tid&3;
      size_t pix=(size_t)b*4096 + (pair==0 ? (c0+r) : (r*64+c));
      float4 bv=*(const float4*)&Bg[(pix*4+dir)*16+q*4];
      float4 cv=*(const float4*)&Cg[(pix*4+dir)*16+q*4];
      u16x4 wb={f2bf(bv.x),f2bf(bv.y),f2bf(bv.z),f2bf(bv.w)};
      u16x4 wc={f2bf(cv.x),f2bf(cv.y),f2bf(cv.z),f2bf(cv.w)};
      u16x4 zz={0,0,0,0};
      *(u16x4*)&Btf[r*32+q*4]=wb;      *(u16x4*)&Btf[r*32+16+q*4]=zz;
      *(u16x4*)&Alds[r*LDK+64+q*4]=wc; *(u16x4*)&Alds[r*LDK+80+q*4]=zz;
    }
    {
      const size_t pbase=(((size_t)(b*64+cd))*24+dir*6)*512;
      int lr=tid>>2, ng=tid&3, hh=lr>>5, dd=lr&31;
      float4 pv=*(const float4*)&Sprev[pbase+(size_t)hh*512+dd*16+ng*4];
      u16x4 w={f2bf(pv.x),f2bf(pv.y),f2bf(pv.z),f2bf(pv.w)};
      u16x4 zz={0,0,0,0};
      *(u16x4*)&Blds[lr*LDK+64+ng*4]=w;
      *(u16x4*)&Blds[lr*LDK+80+ng*4]=zz;
    }
    __syncthreads();
    #pragma unroll
    for(int tt=0;tt<2;tt++){
      int tile=wv+12*tt;
      if(tile<16){
        int mt=tile>>2, nt=tile&3;
        f32x4 a4={0.f,0.f,0.f,0.f};
        bf16x8 af=*(const bf16x8*)&Alds[(mt*16+l15)*LDK+64+l4*8];
        bf16x8 bfr=*(const bf16x8*)&Btf[(nt*16+l15)*32+l4*8];
        a4=__builtin_amdgcn_mfma_f32_16x16x32_bf16(af,bfr,a4,0,0,0);
        #pragma unroll
        for(int r=0;r<4;r++){
          int t=mt*16+l4*4+r, s=nt*16+l15;
          bool keep = d? (s>=t) : (s<=t);
          Alds[t*LDK+s]= keep? f2bf(a4[r]) : (unsigned short)0;
        }
      }
    }
    {
      int sg=tid/48, q=tid-sg*48;
      int head=q>>3;
      f32 vv[4][4];
      #pragma unroll
      for(int j=0;j<4;j++){
        int s=sg*4+j;
        size_t pix=(size_t)b*4096 + (pair==0 ? (c0+s) : (s*64+c));
        float4 xv=*(const float4*)&xh[pix*192 + q*4];
        f32 w1=w1l[d][s][head];
        vv[j][0]=xv.x*w1; vv[j][1]=xv.y*w1; vv[j][2]=xv.z*w1; vv[j][3]=xv.w*w1;
      }
      #pragma unroll
      for(int cc=0;cc<4;cc++){
        u16x4 w={f2bf(vv[0][cc]),f2bf(vv[1][cc]),f2bf(vv[2][cc]),f2bf(vv[3][cc])};
        *(u16x4*)&Blds[(4*q+cc)*LDK+sg*4]=w;
      }
    }
    __syncthreads();
    f32x4 acc[4];
    #pragma unroll
    for(int mt=0;mt<4;mt++){ f32x4 zz={0.f,0.f,0.f,0.f}; acc[mt]=zz; }
    #pragma unroll
    for(int ks=0;ks<3;ks++){
      const int kg=ks*4+l4;
      bf16x8 bfr=*(const bf16x8*)&Blds[(wv*16+l15)*LDK+kg*8];
      #pragma unroll
      for(int mt=0;mt<4;mt++){
        bf16x8 af=*(const bf16x8*)&Alds[(mt*16+l15)*LDK+kg*8];
        acc[mt]=__builtin_amdgcn_mfma_f32_16x16x32_bf16(af,bfr,acc[mt],0,0,0);
      }
    }
    #pragma unroll
    for(int mt=0;mt<4;mt++){
      #pragma unroll
      for(int r=0;r<4;r++){
        int t=mt*16+l4*4+r;
        vsum[mt][r]+=acc[mt][r]*erowl[d][t][ohead];
      }
    }
  }
  #pragma unroll
  for(int mt=0;mt<4;mt++){
    #pragma unroll
    for(int r=0;r<4;r++){
      int t=mt*16+l4*4+r;
      size_t pix=(size_t)b*4096 + (pair==0 ? (c0+t) : (t*64+c));
      ym[pix*192+gch]=vsum[mt][r];
    }
  }
}

// ---------------- Kernel F (MFMA): out = LN(ym0+ym1+x*Dsum)*z @ Wo^T -----------
__global__ __launch_bounds__(256) void k_outproj(const f32* __restrict__ ym0, const f32* __restrict__ ym1,
                                                 const f32* __restrict__ xh, const f32* __restrict__ Dsum,
                                                 const f32* __restrict__ z,
                                                 const f32* __restrict__ lw, const f32* __restrict__ lb,
                                                 const unsigned short* __restrict__ Wo, f32* __restrict__ out){
  __shared__ unsigned short Ald[24*64*8];      // 24 KB
  __shared__ f32 lws[192], lbs[192], dss[192];
  const int m0=blockIdx.x*64, tid=threadIdx.x;
  for(int i=tid;i<192;i+=256){ lws[i]=lw[i]; lbs[i]=lb[i]; dss[i]=Dsum[i]; }
  __syncthreads();
  const int r=tid>>2, sub=tid&3;
  const size_t base=(size_t)(m0+r)*192 + sub*48;
  f32 y[48];
  f32 s=0.f;
  #pragma unroll
  for(int j=0;j<48;j+=4){
    float4 a=*(const float4*)&ym0[base+j];
    float4 bb=*(const float4*)&ym1[base+j];
    float4 xv=*(const float4*)&xh[base+j];
    int col=sub*48+j;
    y[j]  =a.x+bb.x+xv.x*dss[col];
    y[j+1]=a.y+bb.y+xv.y*dss[col+1];
    y[j+2]=a.z+bb.z+xv.z*dss[col+2];
    y[j+3]=a.w+bb.w+xv.w*dss[col+3];
    s+=y[j]+y[j+1]+y[j+2]+y[j+3];
  }
  s+=__shfl_xor(s,1,64); s+=__shfl_xor(s,2,64);
  const f32 mu=s*(1.f/192.f);
  f32 q=0.f;
  #pragma unroll
  for(int j=0;j<48;j++){ f32 dd=y[j]-mu; q+=dd*dd; }
  q+=__shfl_xor(q,1,64); q+=__shfl_xor(q,2,64);
  const f32 rs=rsqrtf(q*(1.f/192.f)+1e-5f);
  #pragma unroll
  for(int j=0;j<48;j+=8){
    float4 z0=*(const float4*)&z[base+j];
    float4 z1=*(const float4*)&z[base+j+4];
    int col=sub*48+j;
    u16x8 w;
    w[0]=f2bf(((y[j+0]-mu)*rs*lws[col+0]+lbs[col+0])*z0.x);
    w[1]=f2bf(((y[j+1]-mu)*rs*lws[col+1]+lbs[col+1])*z0.y);
    w[2]=f2bf(((y[j+2]-mu)*rs*lws[col+2]+lbs[col+2])*z0.z);
    w[3]=f2bf(((y[j+3]-mu)*rs*lws[col+3]+lbs[col+3])*z0.w);
    w[4]=f2bf(((y[j+4]-mu)*rs*lws[col+4]+lbs[col+4])*z1.x);
    w[5]=f2bf(((y[j+5]-mu)*rs*lws[col+5]+lbs[col+5])*z1.y);
    w[6]=f2bf(((y[j+6]-mu)*rs*lws[col+6]+lbs[col+6])*z1.z);
    w[7]=f2bf(((y[j+7]-mu)*rs*lws[col+7]+lbs[col+7])*z1.w);
    int g=col>>3;
    *(u16x8*)&Ald[((size_t)g*64+r)*8]=w;
  }
  __syncthreads();
  const int wv=tid>>6, lane=tid&63, l15=lane&15, l4=lane>>4;
  f32x4 acc[6];
  #pragma unroll
  for(int nt=0;nt<6;nt++){ f32x4 zz={0.f,0.f,0.f,0.f}; acc[nt]=zz; }
  #pragma unroll
  for(int ks=0;ks<6;ks++){
    const int g=ks*4+l4;
    bf16x8 a=*(const bf16x8*)&Ald[(size_t)(g*64+wv*16+l15)*8];
    #pragma unroll
    for(int nt=0;nt<6;nt++){
      bf16x8 bfr=*(const bf16x8*)&Wo[((size_t)(nt*24+g)*16+l15)*8];
      acc[nt]=__builtin_amdgcn_mfma_f32_16x16x32_bf16(a,bfr,acc[nt],0,0,0);
    }
  }
  const int rowb=m0+wv*16+l4*4;
  #pragma unroll
  for(int nt=0;nt<6;nt++){
    int col=nt*16+l15;
    #pragma unroll
    for(int r2=0;r2<4;r2++){
      out[(size_t)(rowb+r2)*96+col]=acc[nt][r2];
    }
  }
}

extern "C" void kernel_launch(void* const* d_in, const int* in_sizes, int n_in,
                              void* d_out, int out_size, void* d_ws, size_t ws_size,
                              hipStream_t stream){
  const f32* x  =(const f32*)d_in[0];
  const f32* ipw=(const f32*)d_in[1];
  const f32* cw =(const f32*)d_in[2];
  const f32* cb =(const f32*)d_in[3];
  const f32* xpw=(const f32*)d_in[4];
  const f32* alg=(const f32*)d_in[5];
  const f32* dsw=(const f32*)d_in[6];
  const f32* dtb=(const f32*)d_in[7];
  const f32* lw =(const f32*)d_in[8];
  const f32* lb =(const f32*)d_in[9];
  const f32* opw=(const f32*)d_in[10];
  f32* out=(f32*)d_out;
  f32* ws=(f32*)d_ws;

  // Workspace budget lesson (R15/R16): ws_size is between 146.0 and 158.6 MB —
  // keep total footprint <= 36,493,504 floats. xhb therefore ALIASES ym1's
  // first half: conv writes it, xdbl/chunk1 read it, then chunk2 overwrites
  // ym1 (chunk2 reads only fp32 xh — no overlap in lifetime).
  f32* xh_raw=ws;               // 6291456 floats (reused as ym0)
  f32* z     =ws+ 6291456;      // 6291456
  f32* xh    =ws+12582912;      // 6291456
  f32* dt_sp =ws+18874368;      //  786432
  f32* Bg    =ws+19660800;      // 2097152
  f32* Cg    =ws+21757952;      // 2097152
  f32* S     =ws+23855104;      // 6291456
  f32* ach   =ws+30146560;      //   12288
  f32* ym1   =ws+30158848;      // 6291456
  unsigned short* Wx=(unsigned short*)(ws+36450304);   // 30720 u16
  unsigned short* Wi=(unsigned short*)(ws+36465664);   // 36864 u16
  unsigned short* Wo=(unsigned short*)(ws+36484096);   // 18432 u16
  f32* Dsum  =ws+36493312;      //     192  (footprint ends at 36,493,504 floats)
  f32* ym0=xh_raw;
  unsigned short* xhb=(unsigned short*)ym1;  // bf16 xh copy, dead before chunk2 writes ym1

  k_wcvt_all<<<43,256,0,stream>>>(xpw,ipw,opw,dsw,Wx,Wi,Wo,Dsum);
  k_inproj<<<1024,256,0,stream>>>(x,Wi,xh_raw,z);
  k_conv<<<6144,256,0,stream>>>(xh_raw,cw,cb,xh,xhb);
  k_xdbl<<<1024,256,0,stream>>>(xhb,Wx,dtb,dt_sp,Bg,Cg);
  k_chunk1<<<dim3(64,4,8),384,0,stream>>>(xhb,Bg,dt_sp,alg,S,ach);
  k_scan<<<384,256,0,stream>>>(S,ach);
  k_chunk2<<<dim3(64,8,2),768,0,stream>>>(xh,Bg,Cg,dt_sp,S,alg,ym0,ym1);
  k_outproj<<<512,256,0,stream>>>(ym0,ym1,xh,Dsum,z,lw,lb,Wo,out);
}